// Round 6
// baseline (175.874 us; speedup 1.0000x reference)
//
#include <hip/hip_runtime.h>
#include <hip/hip_bf16.h>
#include <stdint.h>

#define NB 2
#define SEQ 2048
#define DIM 1024
#define NH 16
#define HD 64

typedef __attribute__((ext_vector_type(4))) float f32x4;
typedef __attribute__((ext_vector_type(16))) float f32x16;
typedef __attribute__((ext_vector_type(8))) short s16x8;
typedef __attribute__((ext_vector_type(4))) short s16x4;
typedef __attribute__((ext_vector_type(8))) __bf16 bf16x8;

static __device__ __forceinline__ short f2bf_rne(float x) {
  uint32_t u = __float_as_uint(x);
  u += 0x7fffu + ((u >> 16) & 1u);
  return (short)(u >> 16);
}
static __device__ __forceinline__ uint32_t pk_bf16(float a, float b) {
  __hip_bfloat162 h = __float22bfloat162_rn(float2{a, b});
  uint32_t u;
  __builtin_memcpy(&u, &h, 4);
  return u;
}
static __device__ __forceinline__ bf16x8 ldfrag(const short* p) {
  bf16x8 r;
  __builtin_memcpy(&r, p, 16);
  return r;
}
static __device__ __forceinline__ void glds16(const short* g, short* l) {
  __builtin_amdgcn_global_load_lds(
      (const __attribute__((address_space(1))) uint32_t*)g,
      (__attribute__((address_space(3))) uint32_t*)l, 16, 0, 0);
}

// ---- fused prep: blocks [0,1024): K -> bf16 FRAGMENT-LINEAR head-major
// (per 64-row kv tile: [kvh][ks][l32][hl][8]); V -> bf16 FRAGMENT-LINEAR
// (per kv tile: [frag = ksg*2+dt][l32][hl][8], content = transposed V with
// kv bit2<->3 swap baked, register-identical to the old LDS path after the
// XOR-swizzle cancellation). Both give attn coalesced 1KB global-direct
// fragment loads -> no LDS, no barriers in attn's main loop.
// blocks [1024,1536): W -> bf16 ---------------------------------------------
__global__ __launch_bounds__(256) void prep_all(const float* __restrict__ K,
                                                const float* __restrict__ V,
                                                const float* __restrict__ W,
                                                short* __restrict__ Kh,
                                                short* __restrict__ Vt,
                                                short* __restrict__ Wh) {
  __shared__ float vtile[64][65];
  const int tid = threadIdx.x;
  const int id = blockIdx.x;

  if (id >= 1024) {  // ---- W convert ----
    size_t idx = ((size_t)(id - 1024) * 256 + tid) * 8;
    f32x4 a = *(const f32x4*)(W + idx);
    f32x4 b = *(const f32x4*)(W + idx + 4);
    s16x8 o;
#pragma unroll
    for (int j = 0; j < 4; ++j) {
      o[j] = f2bf_rne(a[j]);
      o[4 + j] = f2bf_rne(b[j]);
    }
    *(s16x8*)(Wh + idx) = o;
    return;
  }

  const int t0 = (id & 31) * 64;
  const int bh = id >> 5;
  const int b = bh >> 4, h = bh & 15;

#pragma unroll
  for (int i = 0; i < 4; ++i) {
    int f = tid + 256 * i;
    int row = f >> 4;
    int col = (f & 15) * 4;
    const float* src = K + ((size_t)(b * SEQ + t0 + row)) * DIM + h * HD + col;
    f32x4 v = *(const f32x4*)src;
    s16x4 hi;
#pragma unroll
    for (int j = 0; j < 4; ++j) hi[j] = f2bf_rne(v[j]);
    // K fragment-linear: [kvh][ks][l32][hl][8]
    int kvh = row >> 5, l32r = row & 31;
    int ks = col >> 4, hl2 = (col >> 3) & 1, j0 = col & 7;
    *(s16x4*)(Kh + ((size_t)(bh * SEQ + t0)) * HD + kvh * 2048 + ks * 512 +
              l32r * 16 + hl2 * 8 + j0) = hi;
  }
#pragma unroll
  for (int i = 0; i < 4; ++i) {
    int f = tid + 256 * i;
    int row = f >> 4;
    int col = (f & 15) * 4;
    const float* src = V + ((size_t)(b * SEQ + t0 + row)) * DIM + h * HD + col;
    f32x4 v = *(const f32x4*)src;
#pragma unroll
    for (int j = 0; j < 4; ++j) vtile[row][col + j] = v[j];
  }
  __syncthreads();
#pragma unroll
  for (int i = 0; i < 4; ++i) {
    int idx = tid + 256 * i;
    int d = idx >> 4;
    int kb = (idx & 15) * 4;  // 4-aligned kv group
    int kp = (kb & ~12) | ((kb & 4) << 1) | ((kb & 8) >> 1);  // bit2<->3 swap
    s16x4 o4;
#pragma unroll
    for (int j = 0; j < 4; ++j) o4[j] = f2bf_rne(vtile[kb + j][d]);
    // V fragment-linear: per tile [ksg*2+dt][l32][hl][8]; element (d, kv=kp+j)
    int dt = d >> 5, l32r = d & 31;
    int ksg = kp >> 4, hl2 = (kp >> 3) & 1, j0 = kp & 7;
    *(s16x4*)(Vt + ((size_t)(bh * 32 + (t0 >> 6))) * 4096 +
              (ksg * 2 + dt) * 512 + l32r * 16 + hl2 * 8 + j0) = o4;
  }
}

// -------- flash attention: 512 thr = 8 waves, BARRIER-FREE main loop -------
// K and V both read global-direct into registers from fragment-linear
// layouts (1KB dense per wave-load, L1/L2-resident: 512KB KV per bh shared
// by 16 blocks; XCD swizzle pins 4 bh = 2MB to each XCD's L2). No LDS, no
// glds, no __syncthreads until the epilogue -> no convergence stalls
// (R2/R5 post-mortem: ~35-40% of SIMD time was barrier re-convergence,
// invariant under occupancy and LDS-load changes). V loads are JIT: the
// exp2 chain (independent of V) covers L2 latency; K(t+1) prefetched a
// full tile early. Epilogue: PV partials + denominators exact-summed
// across wave pairs via LDS, STATIC acc indexing only (rule #20).
#define QSCALE (0.125f * 1.44269504088896340736f)  // 1/sqrt(64) * log2(e)
#define NT_KV 32                                   // SEQ/64 kv tiles

// QK scores from register K-fragments
static __device__ __forceinline__ f32x16 qkreg(const bf16x8* kf,
                                               const bf16x8* qh) {
  f32x16 s;
#pragma unroll
  for (int r = 0; r < 16; ++r) s[r] = 0.f;
#pragma unroll
  for (int ks = 0; ks < 4; ++ks)
    s = __builtin_amdgcn_mfma_f32_32x32x16_bf16(kf[ks], qh[ks], s, 0, 0, 0);
  return s;
}

// exp + den + pack + PV from register V-fragments (v0,v1 = tp0 dt0/dt1;
// v2,v3 = tp1 dt0/dt1). All indices static under full unroll.
static __device__ __forceinline__ void exppv_reg(const f32x16& sf, bf16x8 v0,
                                                 bf16x8 v1, bf16x8 v2,
                                                 bf16x8 v3, f32x16* acc,
                                                 float& den0, float& den1) {
#pragma unroll
  for (int tp = 0; tp < 2; ++tp) {
    uint32_t w[4];
#pragma unroll
    for (int j2 = 0; j2 < 4; ++j2) {
      float p0 = __builtin_amdgcn_exp2f(sf[tp * 8 + j2 * 2]);
      float p1 = __builtin_amdgcn_exp2f(sf[tp * 8 + j2 * 2 + 1]);
      den0 += p0;
      den1 += p1;
      w[j2] = pk_bf16(p0, p1);
    }
    bf16x8 pa;
    __builtin_memcpy(&pa, w, 16);
    acc[0] = __builtin_amdgcn_mfma_f32_32x32x16_bf16(pa, tp ? v2 : v0, acc[0],
                                                     0, 0, 0);
    acc[1] = __builtin_amdgcn_mfma_f32_32x32x16_bf16(pa, tp ? v3 : v1, acc[1],
                                                     0, 0, 0);
  }
}

__global__ __launch_bounds__(512, 4) void attn(const float* __restrict__ Q,
                                               const short* __restrict__ Kh,
                                               const short* __restrict__ Vt,
                                               short* __restrict__ Ch) {
  __shared__ __align__(16) float xbuf[8192];  // epilogue exchange (32KB)
  __shared__ float dsh[8][64];

  const int tid = threadIdx.x;
  const int wv = tid >> 6, ln = tid & 63;
  const int l32 = ln & 31, hl = ln >> 5;
  const int qsub = wv >> 1, kvh = wv & 1;

  // XCD-chunked swizzle: XCD k (= lin%8) gets bh in [k*4, k*4+4) -> its L2
  // holds those 4 heads' KV (2MB). Bijective for 512 blocks.
  const int lin = blockIdx.y * gridDim.x + blockIdx.x;  // 0..511
  const int nl = ((lin & 7) << 6) | (lin >> 3);
  const int bx = nl & 15, bh = nl >> 4;
  const int b = bh >> 4, hh = bh & 15;
  const int q0 = bx * 128 + qsub * 32;

  // Q B-fragments (single bf16), scale*log2e folded in
  bf16x8 qh[4];
  {
    const float* qp = Q + ((size_t)(b * SEQ + q0 + l32)) * DIM + hh * HD + hl * 8;
#pragma unroll
    for (int ks = 0; ks < 4; ++ks) {
      short th[8];
#pragma unroll
      for (int j = 0; j < 8; ++j) th[j] = f2bf_rne(qp[ks * 16 + j] * QSCALE);
      __builtin_memcpy(&qh[ks], th, 16);
    }
  }

  f32x16 acc[2];
#pragma unroll
  for (int r = 0; r < 16; ++r) {
    acc[0][r] = 0.f;
    acc[1][r] = 0.f;
  }
  float den0 = 0.f, den1 = 0.f;

  // per-lane fragment-linear bases (this wave's kvh half)
  // K frag ks of tile t:      kbase + t*4096 + ks*512
  // V frag (tp,dt) of tile t: vbase + t*4096 + tp*1024 + dt*512
  const short* kbase =
      Kh + (size_t)bh * SEQ * HD + kvh * 2048 + l32 * 16 + hl * 8;
  const short* vbase =
      Vt + (size_t)bh * (SEQ / 64) * 4096 + kvh * 2048 + l32 * 16 + hl * 8;

  // ---- prologue: K(0) -> regs, scores tile 0 ----
  bf16x8 kA[4];
#pragma unroll
  for (int ks = 0; ks < 4; ++ks) kA[ks] = ldfrag(kbase + ks * 512);
  f32x16 sfA = qkreg(kA, qh);

  bf16x8 v0, v1, v2, v3;
  for (int t = 0; t < 30; t += 2) {
    // ---- even tile t ----
    const short* vb0 = vbase + (size_t)t * 4096;
    v0 = ldfrag(vb0);
    v1 = ldfrag(vb0 + 512);
    v2 = ldfrag(vb0 + 1024);
    v3 = ldfrag(vb0 + 1536);
#pragma unroll
    for (int ks = 0; ks < 4; ++ks)
      kA[ks] = ldfrag(kbase + (size_t)(t + 1) * 4096 + ks * 512);
    exppv_reg(sfA, v0, v1, v2, v3, acc, den0, den1);  // tile t
    __builtin_amdgcn_s_setprio(1);
    f32x16 sfB = qkreg(kA, qh);  // tile t+1 scores
    __builtin_amdgcn_s_setprio(0);
    // ---- odd tile t+1 ----
    const short* vb1 = vbase + (size_t)(t + 1) * 4096;
    v0 = ldfrag(vb1);
    v1 = ldfrag(vb1 + 512);
    v2 = ldfrag(vb1 + 1024);
    v3 = ldfrag(vb1 + 1536);
#pragma unroll
    for (int ks = 0; ks < 4; ++ks)
      kA[ks] = ldfrag(kbase + (size_t)(t + 2) * 4096 + ks * 512);
    exppv_reg(sfB, v0, v1, v2, v3, acc, den0, den1);  // tile t+1
    __builtin_amdgcn_s_setprio(1);
    sfA = qkreg(kA, qh);  // tile t+2 scores
    __builtin_amdgcn_s_setprio(0);
  }
  // ---- tile 30 (peeled) ----
  {
    const short* vb0 = vbase + (size_t)30 * 4096;
    v0 = ldfrag(vb0);
    v1 = ldfrag(vb0 + 512);
    v2 = ldfrag(vb0 + 1024);
    v3 = ldfrag(vb0 + 1536);
#pragma unroll
    for (int ks = 0; ks < 4; ++ks)
      kA[ks] = ldfrag(kbase + (size_t)31 * 4096 + ks * 512);
    exppv_reg(sfA, v0, v1, v2, v3, acc, den0, den1);
    __builtin_amdgcn_s_setprio(1);
    sfA = qkreg(kA, qh);  // tile 31 scores
    __builtin_amdgcn_s_setprio(0);
  }
  // ---- tile 31 (peeled) ----
  {
    const short* vb1 = vbase + (size_t)31 * 4096;
    v0 = ldfrag(vb1);
    v1 = ldfrag(vb1 + 512);
    v2 = ldfrag(vb1 + 1024);
    v3 = ldfrag(vb1 + 1536);
    exppv_reg(sfA, v0, v1, v2, v3, acc, den0, den1);
  }

  // ---- epilogue: combine wave pairs (kvh 0/1) via LDS, then store ----
  float den = den0 + den1;
  den += __shfl_xor(den, 32);  // this half's full denominator for q = l32

  // STATIC-index select into named register vectors (rule #20).
  f32x16 give, keep;
  if (kvh == 0) {
    give = acc[1];
    keep = acc[0];
  } else {
    give = acc[0];
    keep = acc[1];
  }

  *(f32x16*)(&xbuf[wv * 1024 + ln * 16]) = give;  // hand partner its block
  dsh[wv][ln] = den;
  __syncthreads();

  float dtot = den + dsh[wv ^ 1][ln];
  float invd = 1.0f / dtot;
  float inv_r[16];
#pragma unroll
  for (int r = 0; r < 16; ++r)
    inv_r[r] = __shfl(invd, (r & 3) + 8 * (r >> 2) + 4 * hl, 64);

  f32x16 oth = *(const f32x16*)(&xbuf[(wv ^ 1) * 1024 + ln * 16]);
#pragma unroll
  for (int r = 0; r < 16; ++r) {
    float cs = keep[r] + oth[r];
    int row = (r & 3) + 8 * (r >> 2) + 4 * hl;
    size_t off =
        ((size_t)(b * SEQ + q0 + row)) * DIM + hh * HD + kvh * 32 + l32;
    Ch[off] = f2bf_rne(cs * inv_r[r]);
  }
}

// ---------------- projection: OUT = ctx @ W^T + b (64x64, grid 1024) --------
__global__ __launch_bounds__(256, 4) void proj(const short* __restrict__ Ah,
                                               const short* __restrict__ Wh,
                                               const float* __restrict__ bias,
                                               float* __restrict__ OUT) {
  __shared__ __align__(16) short ash[2][4096];
  __shared__ __align__(16) short wsh[2][4096];
  const int tid = threadIdx.x;
  const int wv = tid >> 6, ln = tid & 63;
  const int l32 = ln & 31, hl = ln >> 5;
  const int wm = wv & 1, wn = wv >> 1;
  const int m0 = blockIdx.x * 64, n0 = blockIdx.y * 64;

  f32x16 acc;
#pragma unroll
  for (int r = 0; r < 16; ++r) acc[r] = 0.f;

  const int srow8 = ln >> 3, sg = ln & 7;
  const int sw = (sg ^ srow8) * 8;

  // stage k-tile 0: 16 chunks (0-7 A rows, 8-15 W rows), 4 per wave
#pragma unroll
  for (int i = 0; i < 4; ++i) {
    int c = wv * 4 + i;
    int row = (c & 7) * 8 + srow8;
    if (c < 8)
      glds16(Ah + (size_t)(m0 + row) * DIM + sw, ash[0] + (c & 7) * 512);
    else
      glds16(Wh + (size_t)(n0 + row) * DIM + sw, wsh[0] + (c & 7) * 512);
  }

  for (int kt = 0; kt < DIM / 64; ++kt) {
    __syncthreads();
    if (kt + 1 < DIM / 64) {
      const int kk = (kt + 1) * 64;
      const int bn = (kt + 1) & 1;
#pragma unroll
      for (int i = 0; i < 4; ++i) {
        int c = wv * 4 + i;
        int row = (c & 7) * 8 + srow8;
        if (c < 8)
          glds16(Ah + (size_t)(m0 + row) * DIM + kk + sw, ash[bn] + (c & 7) * 512);
        else
          glds16(Wh + (size_t)(n0 + row) * DIM + kk + sw, wsh[bn] + (c & 7) * 512);
      }
    }
    const short* ab = ash[kt & 1];
    const short* wb = wsh[kt & 1];
#pragma unroll
    for (int ks = 0; ks < 4; ++ks) {
      bf16x8 af = ldfrag(ab + (wm * 32 + l32) * 64 + (((ks * 2 + hl) ^ (l32 & 7)) * 8));
      bf16x8 wf = ldfrag(wb + (wn * 32 + l32) * 64 + (((ks * 2 + hl) ^ (l32 & 7)) * 8));
      acc = __builtin_amdgcn_mfma_f32_32x32x16_bf16(af, wf, acc, 0, 0, 0);
    }
  }

  float bs = bias[n0 + wn * 32 + l32];
#pragma unroll
  for (int r = 0; r < 16; ++r) {
    int row = m0 + wm * 32 + (r & 3) + 8 * (r >> 2) + 4 * hl;
    int col = n0 + wn * 32 + l32;
    OUT[(size_t)row * DIM + col] = acc[r] + bs;
  }
}

extern "C" void kernel_launch(void* const* d_in, const int* in_sizes, int n_in,
                              void* d_out, int out_size, void* d_ws, size_t ws_size,
                              hipStream_t stream) {
  const float* Q = (const float*)d_in[0];
  const float* K = (const float*)d_in[1];
  const float* V = (const float*)d_in[2];
  const float* W = (const float*)d_in[3];
  const float* bias = (const float*)d_in[4];
  float* OUT = (float*)d_out;

  char* ws = (char*)d_ws;
  short* Kh = (short*)(ws + ((size_t)0 << 20));   // 8 MB (K fragment-linear)
  short* Vt = (short*)(ws + ((size_t)8 << 20));   // 8 MB (V fragment-linear)
  short* Ch = (short*)(ws + ((size_t)16 << 20));  // 8 MB
  short* Wh = (short*)(ws + ((size_t)24 << 20));  // 2 MB

  prep_all<<<dim3(1536), 256, 0, stream>>>(K, V, W, Kh, Vt, Wh);
  attn<<<dim3(SEQ / 128, NB * NH), 512, 0, stream>>>(Q, Kh, Vt, Ch);
  proj<<<dim3((NB * SEQ) / 64, DIM / 64), 256, 0, stream>>>(Ch, Wh, bias, OUT);
}

// Round 7
// 156.324 us; speedup vs baseline: 1.1251x; 1.1251x over previous
//
#include <hip/hip_runtime.h>
#include <hip/hip_bf16.h>
#include <stdint.h>

#define NB 2
#define SEQ 2048
#define DIM 1024
#define NH 16
#define HD 64

typedef __attribute__((ext_vector_type(4))) float f32x4;
typedef __attribute__((ext_vector_type(16))) float f32x16;
typedef __attribute__((ext_vector_type(8))) short s16x8;
typedef __attribute__((ext_vector_type(4))) short s16x4;
typedef __attribute__((ext_vector_type(8))) __bf16 bf16x8;

static __device__ __forceinline__ short f2bf_rne(float x) {
  uint32_t u = __float_as_uint(x);
  u += 0x7fffu + ((u >> 16) & 1u);
  return (short)(u >> 16);
}
static __device__ __forceinline__ uint32_t pk_bf16(float a, float b) {
  __hip_bfloat162 h = __float22bfloat162_rn(float2{a, b});
  uint32_t u;
  __builtin_memcpy(&u, &h, 4);
  return u;
}
static __device__ __forceinline__ bf16x8 ldfrag(const short* p) {
  bf16x8 r;
  __builtin_memcpy(&r, p, 16);
  return r;
}
static __device__ __forceinline__ void glds16(const short* g, short* l) {
  __builtin_amdgcn_global_load_lds(
      (const __attribute__((address_space(1))) uint32_t*)g,
      (__attribute__((address_space(3))) uint32_t*)l, 16, 0, 0);
}

// ---- fused prep: blocks [0,1024): K -> bf16 FRAGMENT-LINEAR head-major
// (per 64-row kv tile: [kvh][ks][l32][hl][8] so a wave's MFMA A-fragment load
// is one contiguous 1KB segment -> coalesced global-direct reads in attn),
// V -> V^T bf16 head-major with kv bit2<->bit3 swap;
// blocks [1024,1536): W -> bf16 ---------------------------------------------
__global__ __launch_bounds__(256) void prep_all(const float* __restrict__ K,
                                                const float* __restrict__ V,
                                                const float* __restrict__ W,
                                                short* __restrict__ Kh,
                                                short* __restrict__ Vt,
                                                short* __restrict__ Wh) {
  __shared__ float vtile[64][65];
  const int tid = threadIdx.x;
  const int id = blockIdx.x;

  if (id >= 1024) {  // ---- W convert ----
    size_t idx = ((size_t)(id - 1024) * 256 + tid) * 8;
    f32x4 a = *(const f32x4*)(W + idx);
    f32x4 b = *(const f32x4*)(W + idx + 4);
    s16x8 o;
#pragma unroll
    for (int j = 0; j < 4; ++j) {
      o[j] = f2bf_rne(a[j]);
      o[4 + j] = f2bf_rne(b[j]);
    }
    *(s16x8*)(Wh + idx) = o;
    return;
  }

  const int t0 = (id & 31) * 64;
  const int bh = id >> 5;
  const int b = bh >> 4, h = bh & 15;

#pragma unroll
  for (int i = 0; i < 4; ++i) {
    int f = tid + 256 * i;
    int row = f >> 4;
    int col = (f & 15) * 4;
    const float* src = K + ((size_t)(b * SEQ + t0 + row)) * DIM + h * HD + col;
    f32x4 v = *(const f32x4*)src;
    s16x4 hi;
#pragma unroll
    for (int j = 0; j < 4; ++j) hi[j] = f2bf_rne(v[j]);
    // K fragment-linear: [kvh][ks][l32][hl][8]
    int kvh = row >> 5, l32r = row & 31;
    int ks = col >> 4, hl2 = (col >> 3) & 1, j0 = col & 7;
    *(s16x4*)(Kh + ((size_t)(bh * SEQ + t0)) * HD + kvh * 2048 + ks * 512 +
              l32r * 16 + hl2 * 8 + j0) = hi;
  }
#pragma unroll
  for (int i = 0; i < 4; ++i) {
    int f = tid + 256 * i;
    int row = f >> 4;
    int col = (f & 15) * 4;
    const float* src = V + ((size_t)(b * SEQ + t0 + row)) * DIM + h * HD + col;
    f32x4 v = *(const f32x4*)src;
#pragma unroll
    for (int j = 0; j < 4; ++j) vtile[row][col + j] = v[j];
  }
  __syncthreads();
#pragma unroll
  for (int i = 0; i < 4; ++i) {
    int idx = tid + 256 * i;
    int d = idx >> 4;
    int kb = (idx & 15) * 4;  // 4-aligned kv group
    int kp = (kb & ~12) | ((kb & 4) << 1) | ((kb & 8) >> 1);  // bit2<->3 swap
    s16x4 o4;
#pragma unroll
    for (int j = 0; j < 4; ++j) o4[j] = f2bf_rne(vtile[kb + j][d]);
    *(s16x4*)(Vt + ((size_t)bh * HD + d) * SEQ + t0 + kp) = o4;
  }
}

// -------- flash attention (R5 verbatim, measured 56 us): 512 thr = 8 waves,
// kv-split wave pairs. K global-direct from fragment-linear Kh; V LDS-staged
// double-buffered. Epilogue exact-sums PV partials + denominators across
// wave pairs via LDS, STATIC acc indexing only (rule #20). ------------------
#define QSCALE (0.125f * 1.44269504088896340736f)  // 1/sqrt(64) * log2(e)
#define NT_KV 32                                   // SEQ/64 kv tiles

static __device__ __forceinline__ void exppv32(const f32x16& sf, const short* vb,
                                               int kvh, int l32, int hl,
                                               f32x16* acc, float& den0,
                                               float& den1) {
#pragma unroll
  for (int tp = 0; tp < 2; ++tp) {
    uint32_t w[4];
#pragma unroll
    for (int j2 = 0; j2 < 4; ++j2) {
      float p0 = __builtin_amdgcn_exp2f(sf[tp * 8 + j2 * 2]);
      float p1 = __builtin_amdgcn_exp2f(sf[tp * 8 + j2 * 2 + 1]);
      den0 += p0;
      den1 += p1;
      w[j2] = pk_bf16(p0, p1);
    }
    bf16x8 pa;
    __builtin_memcpy(&pa, w, 16);
    const int ksg = kvh * 2 + tp;
#pragma unroll
    for (int dt = 0; dt < 2; ++dt) {
      bf16x8 vf = ldfrag(vb + (dt * 32 + l32) * 64 +
                         (((ksg * 2 + hl) ^ (l32 & 7)) * 8));
      acc[dt] =
          __builtin_amdgcn_mfma_f32_32x32x16_bf16(pa, vf, acc[dt], 0, 0, 0);
    }
  }
}

// QK scores from register K-fragments
static __device__ __forceinline__ f32x16 qkreg(const bf16x8* kf,
                                               const bf16x8* qh) {
  f32x16 s;
#pragma unroll
  for (int r = 0; r < 16; ++r) s[r] = 0.f;
#pragma unroll
  for (int ks = 0; ks < 4; ++ks)
    s = __builtin_amdgcn_mfma_f32_32x32x16_bf16(kf[ks], qh[ks], s, 0, 0, 0);
  return s;
}

__global__ __launch_bounds__(512, 4) void attn(const float* __restrict__ Q,
                                               const short* __restrict__ Kh,
                                               const short* __restrict__ Vt,
                                               short* __restrict__ Ch) {
  __shared__ __align__(16) short vbuf[2][4096];
  __shared__ __align__(16) float xbuf[4096];  // epilogue exchange, waves 0-3
  __shared__ float dsh[8][64];

  const int tid = threadIdx.x;
  const int wv = tid >> 6, ln = tid & 63;
  const int l32 = ln & 31, hl = ln >> 5;
  const int qsub = wv >> 1, kvh = wv & 1;
  const int bh = blockIdx.y, b = bh >> 4, hh = bh & 15;
  const int q0 = blockIdx.x * 128 + qsub * 32;

  // Q B-fragments (single bf16), scale*log2e folded in
  bf16x8 qh[4];
  {
    const float* qp = Q + ((size_t)(b * SEQ + q0 + l32)) * DIM + hh * HD + hl * 8;
#pragma unroll
    for (int ks = 0; ks < 4; ++ks) {
      short th[8];
#pragma unroll
      for (int j = 0; j < 8; ++j) th[j] = f2bf_rne(qp[ks * 16 + j] * QSCALE);
      __builtin_memcpy(&qh[ks], th, 16);
    }
  }

  f32x16 acc[2];
#pragma unroll
  for (int r = 0; r < 16; ++r) {
    acc[0][r] = 0.f;
    acc[1][r] = 0.f;
  }
  float den0 = 0.f, den1 = 0.f;

  // per-lane K base in fragment-linear layout: + kvh half + lane slot.
  // fragment ks of tile t = khg + t*4096 + ks*512 (each wave-load = 1KB dense)
  const short* khg =
      Kh + (size_t)bh * SEQ * HD + kvh * 2048 + l32 * 16 + hl * 8;
  const short* vtg = Vt + (size_t)bh * HD * SEQ;

  const int srow8 = ln >> 3;  // row-in-chunk 0..7
  const int sg = ln & 7;      // granule 0..7
  const int sw = (sg ^ srow8) * 8;
  const int srow = wv * 8 + srow8;  // V staging row: one chunk per wave

  // ---- prologue: kf(0) -> regs, stage V(0) -> vbuf[0], scores tile 0 ----
  bf16x8 kf0[4];
#pragma unroll
  for (int ks = 0; ks < 4; ++ks) kf0[ks] = ldfrag(khg + ks * 512);
  glds16(vtg + (size_t)srow * SEQ + sw, &vbuf[0][wv * 512]);
  f32x16 sfA = qkreg(kf0, qh);

  for (int t = 0; t < 30; t += 2) {
    // ---- even tile t ----
    __syncthreads();  // V(t) visible in vbuf[0]
    bf16x8 kfa[4];
#pragma unroll
    for (int ks = 0; ks < 4; ++ks)
      kfa[ks] = ldfrag(khg + (t + 1) * 4096 + ks * 512);
    glds16(vtg + (size_t)srow * SEQ + (t + 1) * 64 + sw, &vbuf[1][wv * 512]);
    exppv32(sfA, &vbuf[0][0], kvh, l32, hl, acc, den0, den1);  // tile t
    f32x16 sfB = qkreg(kfa, qh);                               // tile t+1
    // ---- odd tile t+1 ----
    __syncthreads();  // V(t+1) visible in vbuf[1]
    bf16x8 kfb[4];
#pragma unroll
    for (int ks = 0; ks < 4; ++ks)
      kfb[ks] = ldfrag(khg + (t + 2) * 4096 + ks * 512);
    glds16(vtg + (size_t)srow * SEQ + (t + 2) * 64 + sw, &vbuf[0][wv * 512]);
    exppv32(sfB, &vbuf[1][0], kvh, l32, hl, acc, den0, den1);  // tile t+1
    sfA = qkreg(kfb, qh);                                      // tile t+2
  }
  // ---- tile 30 (peeled) ----
  __syncthreads();  // V(30) visible in vbuf[0]
  bf16x8 kfl[4];
#pragma unroll
  for (int ks = 0; ks < 4; ++ks) kfl[ks] = ldfrag(khg + 31 * 4096 + ks * 512);
  glds16(vtg + (size_t)srow * SEQ + 31 * 64 + sw, &vbuf[1][wv * 512]);
  exppv32(sfA, &vbuf[0][0], kvh, l32, hl, acc, den0, den1);
  f32x16 sfT = qkreg(kfl, qh);  // tile 31 scores
  // ---- tile 31 (peeled) ----
  __syncthreads();  // V(31) visible in vbuf[1]
  exppv32(sfT, &vbuf[1][0], kvh, l32, hl, acc, den0, den1);

  // ---- epilogue: combine wave pairs (kvh 0/1) via LDS, then store ----
  float den = den0 + den1;
  den += __shfl_xor(den, 32);  // this half's full denominator for q = l32

  // STATIC-index select into named register vectors (rule #20).
  f32x16 give, keep;
  if (kvh == 0) {
    give = acc[1];
    keep = acc[0];
  } else {
    give = acc[0];
    keep = acc[1];
  }

  __syncthreads();  // all LDS tile reads done; vbuf safe to reuse as scratch
  float* xr = (wv < 4) ? &xbuf[0] : (float*)&vbuf[0][0];
  *(f32x16*)(xr + (wv & 3) * 1024 + ln * 16) = give;  // hand partner its block
  dsh[wv][ln] = den;
  __syncthreads();

  float dtot = den + dsh[wv ^ 1][ln];
  float invd = 1.0f / dtot;
  float inv_r[16];
#pragma unroll
  for (int r = 0; r < 16; ++r)
    inv_r[r] = __shfl(invd, (r & 3) + 8 * (r >> 2) + 4 * hl, 64);

  f32x16 oth = *(const f32x16*)(xr + ((wv ^ 1) & 3) * 1024 + ln * 16);
#pragma unroll
  for (int r = 0; r < 16; ++r) {
    float cs = keep[r] + oth[r];
    int row = (r & 3) + 8 * (r >> 2) + 4 * hl;
    size_t off =
        ((size_t)(b * SEQ + q0 + row)) * DIM + hh * HD + kvh * 32 + l32;
    Ch[off] = f2bf_rne(cs * inv_r[r]);
  }
}

// ---- projection v2: OUT = ctx @ W^T + b, 128x128 tile, BK=64, 512 thr -----
// R6 post-mortem: old 64x64/1024-block proj had 4 MFMA per wave per barrier
// interval (barrier-cadence bound) and A-tiles re-fetched by 16 dispatch-
// scattered n-blocks. New: grid (32 m, 8 n); 8 waves (wm=wv>>1 m-quarter,
// wn=wv&1 n-half), 8 MFMA/wave/kt, 16 kt, 64KB double-buffered LDS
// (2 blocks/CU). Natural dispatch puts m%8 on XCD lin%8: each XCD reads
// 4 A-tiles (1MB) + W (2MB) = 3MB < 4MB L2 -> A fetched from HBM once.
__global__ __launch_bounds__(512, 4) void proj(const short* __restrict__ Ah,
                                               const short* __restrict__ Wh,
                                               const float* __restrict__ bias,
                                               float* __restrict__ OUT) {
  __shared__ __align__(16) short ash[2][8192];
  __shared__ __align__(16) short wsh[2][8192];
  const int tid = threadIdx.x;
  const int wv = tid >> 6, ln = tid & 63;
  const int l32 = ln & 31, hl = ln >> 5;
  const int wm = wv >> 1, wn = wv & 1;
  const int m0 = blockIdx.x * 128, n0 = blockIdx.y * 128;

  f32x16 acc0, acc1;
#pragma unroll
  for (int r = 0; r < 16; ++r) {
    acc0[r] = 0.f;
    acc1[r] = 0.f;
  }

  const int srow8 = ln >> 3, sg = ln & 7;
  const int sw = (sg ^ srow8) * 8;

  // stage k-tile 0: 32 chunks (0-15 A rows, 16-31 W rows), 4 per wave
#pragma unroll
  for (int i = 0; i < 4; ++i) {
    int c = wv * 4 + i;
    int r8 = (c & 15) * 8 + srow8;
    if (c < 16)
      glds16(Ah + (size_t)(m0 + r8) * DIM + sw, ash[0] + (c & 15) * 512);
    else
      glds16(Wh + (size_t)(n0 + r8) * DIM + sw, wsh[0] + (c & 15) * 512);
  }

  for (int kt = 0; kt < DIM / 64; ++kt) {
    __syncthreads();
    if (kt + 1 < DIM / 64) {
      const int kk = (kt + 1) * 64;
      const int bn = (kt + 1) & 1;
#pragma unroll
      for (int i = 0; i < 4; ++i) {
        int c = wv * 4 + i;
        int r8 = (c & 15) * 8 + srow8;
        if (c < 16)
          glds16(Ah + (size_t)(m0 + r8) * DIM + kk + sw, ash[bn] + (c & 15) * 512);
        else
          glds16(Wh + (size_t)(n0 + r8) * DIM + kk + sw, wsh[bn] + (c & 15) * 512);
      }
    }
    const short* ab = ash[kt & 1];
    const short* wb = wsh[kt & 1];
#pragma unroll
    for (int ks = 0; ks < 4; ++ks) {
      int swz = ((ks * 2 + hl) ^ (l32 & 7)) * 8;
      bf16x8 af = ldfrag(ab + (wm * 32 + l32) * 64 + swz);
      bf16x8 wf0 = ldfrag(wb + (wn * 64 + l32) * 64 + swz);
      bf16x8 wf1 = ldfrag(wb + (wn * 64 + 32 + l32) * 64 + swz);
      acc0 = __builtin_amdgcn_mfma_f32_32x32x16_bf16(af, wf0, acc0, 0, 0, 0);
      acc1 = __builtin_amdgcn_mfma_f32_32x32x16_bf16(af, wf1, acc1, 0, 0, 0);
    }
  }

  float bs0 = bias[n0 + wn * 64 + l32];
  float bs1 = bias[n0 + wn * 64 + 32 + l32];
#pragma unroll
  for (int r = 0; r < 16; ++r) {
    int row = m0 + wm * 32 + (r & 3) + 8 * (r >> 2) + 4 * hl;
    int col = n0 + wn * 64 + l32;
    OUT[(size_t)row * DIM + col] = acc0[r] + bs0;
    OUT[(size_t)row * DIM + col + 32] = acc1[r] + bs1;
  }
}

extern "C" void kernel_launch(void* const* d_in, const int* in_sizes, int n_in,
                              void* d_out, int out_size, void* d_ws, size_t ws_size,
                              hipStream_t stream) {
  const float* Q = (const float*)d_in[0];
  const float* K = (const float*)d_in[1];
  const float* V = (const float*)d_in[2];
  const float* W = (const float*)d_in[3];
  const float* bias = (const float*)d_in[4];
  float* OUT = (float*)d_out;

  char* ws = (char*)d_ws;
  short* Kh = (short*)(ws + ((size_t)0 << 20));   // 8 MB (K fragment-linear)
  short* Vt = (short*)(ws + ((size_t)8 << 20));   // 8 MB (V^T, kv bit2<->3)
  short* Ch = (short*)(ws + ((size_t)16 << 20));  // 8 MB
  short* Wh = (short*)(ws + ((size_t)24 << 20));  // 2 MB

  prep_all<<<dim3(1536), 256, 0, stream>>>(K, V, W, Kh, Vt, Wh);
  attn<<<dim3(SEQ / 128, NB * NH), 512, 0, stream>>>(Q, Kh, Vt, Ch);
  proj<<<dim3((NB * SEQ) / 128, DIM / 128), 512, 0, stream>>>(Ch, Wh, bias, OUT);
}